// Round 12
// baseline (308.806 us; speedup 1.0000x reference)
//
#include <hip/hip_runtime.h>
#include <hip/hip_cooperative_groups.h>

namespace cg = cooperative_groups;

// TorchPatchNN: unfold(7x7) -> NN argmin over 8100 keys (D=147) -> gather value -> fold mean.
// Round 17: cooperative fusion, second attempt. R16's zero-output failure (absmax == max|ref|)
//  = launch never ran: 33.8KB block LDS -> occupancy validator (64KB shared/CU cap) -> 1
//  block/CU -> max coop grid 256 < 512 -> hipErrorCooperativeLaunchTooLarge, unchecked.
//  Fixes:
//   (1) epilogue reduction buffer [128][33] -> [128][17] u64 (17.4KB) via shfl_xor(1)
//       col-pair pre-combine (u64 lexicographic min == same tie rule). 2x17.4=34.8KB < 64KB
//       -> 2 blocks/CU passes validation for the 512-block grid.
//   (2) return code CHECKED; on any error fall back to the proven 3-launch R14 path
//       (same ws layout, same numerics) -> this round cannot lose to R14.
//  Phases: prep (grid-stride) | fence+grid.sync | nn 8 tiles/block (qt constant per block,
//  Q L2-hot) | fence+grid.sync | fold (grid-stride). Device-scope fences per G16.
//  If fused runs: k_all ~78-90us, total ~100-125. If fallback: total ~143-147.

#define NQ 8100
#define NK 8100
#define DD 147
#define HO 90
#define IMG 96
#define NCH 5                 // K chunks of 32 (160 padded K)
#define CST 262144            // f16 per chunk plane: 512 groups x 512
#define ARRN (NCH * CST)      // f16 per array
#define GRID 512
#define GSIZE (GRID * 256)

typedef _Float16 half8 __attribute__((ext_vector_type(8)));
typedef float f32x4 __attribute__((ext_vector_type(4)));

// ---------- shared device helpers (identical math in fused and fallback paths) ----------
__device__ __forceinline__ void prep_item(int t, bool isK,
                                          const float* __restrict__ query,
                                          const float* __restrict__ key,
                                          _Float16* __restrict__ Qh, _Float16* __restrict__ Ql,
                                          _Float16* __restrict__ Kh, _Float16* __restrict__ Kl) {
    int c = t >> 15;                            // chunk
    int rem = t & 32767;                        // g*64 + lane
    int col = ((rem >> 6) << 4) + (rem & 15);   // g*16 + l15
    int quad4 = (rem >> 4) & 3;
    int kbase = c * 32 + quad4 * 8;

    float v[8];
#pragma unroll
    for (int j = 0; j < 8; ++j) {
        int k = kbase + j;
        float x = 0.f;
        if (k < DD && col < NQ) {
            if (isK) {
                x = key[col * DD + k];
            } else {
                int c3 = k / 49, r2 = k - 49 * c3;
                int rr = r2 / 7, ss = r2 - 7 * rr;
                int y = col / HO, xx = col - HO * y;
                x = query[(c3 * IMG + y + rr) * IMG + xx + ss];
            }
        }
        v[j] = x;
    }
    half8 h8, l8;
#pragma unroll
    for (int j = 0; j < 8; ++j) {
        _Float16 h = (_Float16)v[j];
        h8[j] = h;
        l8[j] = (_Float16)(v[j] - (float)h);   // UNSCALED lo (merged-acc scheme)
    }
    if (isK) {
        *(half8*)(Kh + t * 8) = h8;
        *(half8*)(Kl + t * 8) = l8;
    } else {
        *(half8*)(Qh + t * 8) = h8;
        *(half8*)(Ql + t * 8) = l8;
    }
}

// nn tile body: barrier-free K-loop, merged acc[4][4], reduced-LDS epilogue ([128][17] u64).
__device__ __forceinline__ void nn_tile(int b, int tid, char* smem,
                                        const _Float16* __restrict__ Qh, const _Float16* __restrict__ Ql,
                                        const _Float16* __restrict__ Kh, const _Float16* __restrict__ Kl,
                                        const float* __restrict__ kn,
                                        unsigned long long* __restrict__ fidx64) {
    const int wave = tid >> 6, lane = tid & 63;
    const int l15 = lane & 15, quad = lane >> 4;

    const int xcd = b & 7;
    const int i2 = b >> 3;
    const int qt = (xcd >> 1) * 16 + (i2 & 15);
    const int kt = (xcd & 1) * 32 + (i2 >> 4);
    const int q0 = qt * 128, n0 = kt * 128;

    const int mbase = (wave >> 1) * 64;
    const int nbase = (wave & 1) * 64;
    const int agrp = (mbase >> 4);
    const int bgrp = (nbase >> 4);

    const _Float16* gQh = Qh + (qt * 8 + agrp) * 512 + lane * 8;
    const _Float16* gQl = Ql + (qt * 8 + agrp) * 512 + lane * 8;
    const _Float16* gKh = Kh + (kt * 8 + bgrp) * 512 + lane * 8;
    const _Float16* gKl = Kl + (kt * 8 + bgrp) * 512 + lane * 8;

    f32x4 acc[4][4];
#pragma unroll
    for (int ii = 0; ii < 4; ++ii)
#pragma unroll
        for (int j = 0; j < 4; ++j)
            acc[ii][j] = (f32x4)0.f;

#pragma unroll
    for (int c = 0; c < NCH; ++c) {
        half8 ah[4], al[4], bh[4], bl[4];
#pragma unroll
        for (int mt = 0; mt < 4; ++mt) {
            ah[mt] = *(const half8*)(gQh + c * CST + mt * 512);
            al[mt] = *(const half8*)(gQl + c * CST + mt * 512);
        }
#pragma unroll
        for (int nt = 0; nt < 4; ++nt) {
            bh[nt] = *(const half8*)(gKh + c * CST + nt * 512);
            bl[nt] = *(const half8*)(gKl + c * CST + nt * 512);
        }

        __builtin_amdgcn_s_setprio(1);
#pragma unroll
        for (int nt = 0; nt < 4; ++nt) {
#pragma unroll
            for (int mt = 0; mt < 4; ++mt) {
                acc[mt][nt] = __builtin_amdgcn_mfma_f32_16x16x32_f16(ah[mt], bh[nt], acc[mt][nt], 0, 0, 0);
                acc[mt][nt] = __builtin_amdgcn_mfma_f32_16x16x32_f16(ah[mt], bl[nt], acc[mt][nt], 0, 0, 0);
                acc[mt][nt] = __builtin_amdgcn_mfma_f32_16x16x32_f16(al[mt], bh[nt], acc[mt][nt], 0, 0, 0);
            }
        }
        __builtin_amdgcn_s_setprio(0);
    }

    // epilogue: dist = kn - 2*acc; packed order-preserving u64; shfl col-pair combine so
    // LDS is [128][17] u64 = 17408 B (< 32KB: keeps 2 blocks/CU past the coop validator).
    float knv[4];
    int nglob[4];
#pragma unroll
    for (int nt = 0; nt < 4; ++nt) {
        nglob[nt] = n0 + nbase + nt * 16 + l15;
        knv[nt] = kn[nglob[nt]];
    }
    unsigned long long* redu = (unsigned long long*)smem;   // [128][17] u64
    const int cidx2 = (nbase >> 3) + (l15 >> 1);            // 0..15 after pair-combine

#pragma unroll
    for (int mt = 0; mt < 4; ++mt)
#pragma unroll
        for (int r = 0; r < 4; ++r) {
            float bv = 1e38f;
            int bn = 0x7fffffff;
#pragma unroll
            for (int nt = 0; nt < 4; ++nt) {   // ascending n within lane -> strict < ok
                float d = knv[nt] - 2.0f * acc[mt][nt][r];
                if (d < bv) { bv = d; bn = nglob[nt]; }
            }
            unsigned u = __float_as_uint(bv);
            u = (u & 0x80000000u) ? ~u : (u | 0x80000000u);   // order-preserving map
            unsigned long long pk = ((unsigned long long)u << 32) | (unsigned)bn;
            unsigned long long po = __shfl_xor(pk, 1, 64);    // partner col, same row
            pk = (po < pk) ? po : pk;
            if (!(lane & 1)) {
                int m = mbase + mt * 16 + quad * 4 + r;        // C row = quad*4 + reg
                redu[m * 17 + cidx2] = pk;
            }
        }
    __syncthreads();

    {   // 2 threads/row, 8 u64-min each, pair-combine via shfl
        int row = tid >> 1;
        int base = (tid & 1) * 8;
        unsigned long long best = 0xFFFFFFFFFFFFFFFFull;
        const unsigned long long* rp = redu + row * 17 + base;
#pragma unroll
        for (int t2 = 0; t2 < 8; ++t2) {
            unsigned long long v = rp[t2];
            best = (v < best) ? v : best;
        }
        unsigned long long other = __shfl_xor(best, 1, 64);
        best = (other < best) ? other : best;
        if (!(tid & 1)) atomicMin(&fidx64[q0 + row], best);
    }
    __syncthreads();   // protect redu for any next tile
}

__device__ __forceinline__ void fold_item(int t, const float* __restrict__ value,
                                          const unsigned long long* __restrict__ fidx64,
                                          float* __restrict__ out) {
    int pix = t >> 3, s = t & 7;
    int c = pix / (IMG * IMG);
    int rem = pix % (IMG * IMG);
    int Y = rem / IMG, X = rem % IMG;

    float partial = 0.f;
    int yy = Y - s;
    if (s < 7 && (unsigned)yy < (unsigned)HO) {
        const unsigned* fidx32 = (const unsigned*)fidx64;   // low word = row index
        const float* vbase = value + c * 49 + s * 7;
        int rows[7];
        bool oks[7];
#pragma unroll
        for (int j = 0; j < 7; ++j) {
            int xx = X - j;
            bool ok = (unsigned)xx < (unsigned)HO;
            int p = ok ? (yy * HO + xx) : 0;
            rows[j] = (int)fidx32[2 * p];
            oks[j] = ok;
        }
#pragma unroll
        for (int j = 0; j < 7; ++j) {
            float v = vbase[rows[j] * DD + j];   // always in-bounds (row 0 when masked)
            if (oks[j]) partial += v;
        }
    }
    partial += __shfl_down(partial, 4, 8);
    partial += __shfl_down(partial, 2, 8);
    partial += __shfl_down(partial, 1, 8);
    if (s == 0) {
        int i0 = max(0, Y - (HO - 1)), i1 = min(6, Y);
        int j0 = max(0, X - (HO - 1)), j1 = min(6, X);
        float cnt = (float)((i1 - i0 + 1) * (j1 - j0 + 1));
        out[pix] = partial / cnt;
    }
}

// ================================ fused cooperative kernel ================================
__launch_bounds__(256, 2)
__global__ void k_all(const float* __restrict__ query, const float* __restrict__ key,
                      const float* __restrict__ value,
                      _Float16* __restrict__ Qh, _Float16* __restrict__ Ql,
                      _Float16* __restrict__ Kh, _Float16* __restrict__ Kl,
                      float* __restrict__ kn, unsigned long long* __restrict__ fidx64,
                      float* __restrict__ out) {
    __shared__ __align__(16) char smem[17408];   // nn epilogue: [128][17] u64

    const int tid = (int)threadIdx.x;
    const int bid = (int)blockIdx.x;
    const int gtid = bid * 256 + tid;
    const int lane = tid & 63;

    // phase 1: prep
    for (int item = gtid; item < 2 * (ARRN / 8); item += GSIZE) {
        const bool isK = item >= (ARRN / 8);
        prep_item(isK ? item - (ARRN / 8) : item, isK, query, key, Qh, Ql, Kh, Kl);
    }
    {   // key norms + fidx poison: 2048 waves x 4 keys = 8192
        int wid = gtid >> 6;
        int kb = wid * 4;
        for (int r = 0; r < 4; ++r) {
            int k = kb + r;
            float s = 0.f;
            if (k < NK)
                for (int d = lane; d < DD; d += 64) {
                    float v = key[k * DD + d];
                    s += v * v;
                }
#pragma unroll
            for (int off = 32; off; off >>= 1) s += __shfl_down(s, off, 64);
            if (lane == 0) {
                kn[k] = (k < NK) ? s : 1e30f;
                fidx64[k] = 0xFFFFFFFFFFFFFFFFull;
            }
        }
    }
    __threadfence();
    cg::this_grid().sync();

    // phase 2: nn, 8 tiles/block (4096/512 exact; qt constant per block -> Q hot)
    for (int b = bid; b < 4096; b += GRID)
        nn_tile(b, tid, smem, Qh, Ql, Kh, Kl, kn, fidx64);
    __threadfence();
    cg::this_grid().sync();

    // phase 3: fold
    for (int t = gtid; t < 3 * IMG * IMG * 8; t += GSIZE)
        fold_item(t, value, fidx64, out);
}

// ================================ fallback 3-launch path ================================
__global__ void k_prep(const float* __restrict__ query, const float* __restrict__ key,
                       _Float16* __restrict__ Qh, _Float16* __restrict__ Ql,
                       _Float16* __restrict__ Kh, _Float16* __restrict__ Kl,
                       float* __restrict__ kn, unsigned long long* __restrict__ fidx64) {
    const int bx = blockIdx.x;
    const bool isK = (blockIdx.y != 0);
    if (bx >= 640) {
        if (!isK) return;
        int wave = threadIdx.x >> 6, lane = threadIdx.x & 63;
        int kb = ((bx - 640) * 4 + wave) * 16;
        for (int r = 0; r < 16; ++r) {
            int k = kb + r;
            float s = 0.f;
            if (k < NK)
                for (int d = lane; d < DD; d += 64) {
                    float v = key[k * DD + d];
                    s += v * v;
                }
#pragma unroll
            for (int off = 32; off; off >>= 1) s += __shfl_down(s, off, 64);
            if (lane == 0) {
                kn[k] = (k < NK) ? s : 1e30f;
                fidx64[k] = 0xFFFFFFFFFFFFFFFFull;
            }
        }
        return;
    }
    prep_item(bx * 256 + threadIdx.x, isK, query, key, Qh, Ql, Kh, Kl);
}

__launch_bounds__(256, 3)
__global__ void k_nn(const _Float16* __restrict__ Qh, const _Float16* __restrict__ Ql,
                     const _Float16* __restrict__ Kh, const _Float16* __restrict__ Kl,
                     const float* __restrict__ kn, unsigned long long* __restrict__ out) {
    __shared__ __align__(16) char smem[17408];
    nn_tile((int)blockIdx.x, (int)threadIdx.x, smem, Qh, Ql, Kh, Kl, kn, out);
}

__global__ void k_fold(const float* __restrict__ value,
                       const unsigned long long* __restrict__ fidx64,
                       float* __restrict__ out) {
    int t = blockIdx.x * 256 + threadIdx.x;
    if (t < 3 * IMG * IMG * 8) fold_item(t, value, fidx64, out);
}

extern "C" void kernel_launch(void* const* d_in, const int* in_sizes, int n_in,
                              void* d_out, int out_size, void* d_ws, size_t ws_size,
                              hipStream_t stream) {
    const float* query = (const float*)d_in[0];
    const float* key   = (const float*)d_in[1];
    const float* value = (const float*)d_in[2];
    float* out = (float*)d_out;

    _Float16* Qh = (_Float16*)d_ws;           // ARRN f16 each
    _Float16* Ql = Qh + ARRN;
    _Float16* Kh = Ql + ARRN;
    _Float16* Kl = Kh + ARRN;
    float* kn = (float*)(Kl + ARRN);          // 8192 f32
    unsigned long long* fidx64 = (unsigned long long*)(kn + 8192);   // 8192 u64

    void* args[] = {(void*)&query, (void*)&key, (void*)&value,
                    (void*)&Qh, (void*)&Ql, (void*)&Kh, (void*)&Kl,
                    (void*)&kn, (void*)&fidx64, (void*)&out};
    hipError_t e = hipLaunchCooperativeKernel((const void*)k_all, dim3(GRID), dim3(256),
                                              args, 0, stream);
    if (e != hipSuccess) {
        (void)hipGetLastError();   // clear sticky error, fall back to proven 3-launch path
        dim3 gp(768, 2);
        k_prep<<<gp, 256, 0, stream>>>(query, key, Qh, Ql, Kh, Kl, kn, fidx64);
        k_nn<<<4096, 256, 0, stream>>>(Qh, Ql, Kh, Kl, kn, fidx64);
        k_fold<<<864, 256, 0, stream>>>(value, fidx64, out);
    }
}

// Round 13
// 141.732 us; speedup vs baseline: 2.1788x; 2.1788x over previous
//
#include <hip/hip_runtime.h>

// TorchPatchNN: unfold(7x7) -> NN argmin over 8100 keys (D=147) -> gather value -> fold mean.
// Round 18: consolidation after two failed structural experiments.
//  R17 verdict: cooperative fusion REFUTED on this chip. Fused k_all = 247us vs ~100-115
//  sum-of-parts: __threadfence (device scope on non-coherent per-XCD L2 = full L2
//  writeback/inval; FETCH 15.5->25.7MB shows frag re-fetch) + grid.sync release/acquire
//  fencing across 512 blocks costs ~130-150us. Inter-launch gaps (~64us for 3 launches)
//  are CHEAPER than one in-kernel global barrier pair. Back to 3 launches.
//  Kernel = R14 structure (best: k_nn 65.8us, total 143.6): barrier-free K-loop, merged
//  acc[4][4] (64 AGPR, lo-planes UNSCALED), 16x16x32 MFMA (R15 proved 32x32 loses: 4 acc
//  chains RAW-serialize), A+B direct from L2 (R8-vs-R12 proved staging parity; direct is
//  simpler + regs lower), launch_bounds(256,3) (R14: occ 20->26.8%, 71.4->65.8us).
//  One delta: [128][17] u64 epilogue (shfl_xor col-pair pre-combine; validated in R17's
//  fused phase 2): LDS 33.8->17.4KB, scan 16->8 u64/thread. Diagnostic: if occupancy rises
//  toward 37%, LDS was capping the 3rd block; if flat, remaining ~63us is launch/harness
//  fixed overhead and we are near the practical floor.

#define NQ 8100
#define NK 8100
#define DD 147
#define HO 90
#define IMG 96
#define NCH 5                 // K chunks of 32 (160 padded K)
#define CST 262144            // f16 per chunk plane: 512 groups x 512
#define ARRN (NCH * CST)      // f16 per array

typedef _Float16 half8 __attribute__((ext_vector_type(8)));
typedef float f32x4 __attribute__((ext_vector_type(4)));

// ---------------- prep: split Q/K into fp16 hi/lo (frag order) + key norms + init ---------
__global__ void k_prep(const float* __restrict__ query, const float* __restrict__ key,
                       _Float16* __restrict__ Qh, _Float16* __restrict__ Ql,
                       _Float16* __restrict__ Kh, _Float16* __restrict__ Kl,
                       float* __restrict__ kn, unsigned long long* __restrict__ fidx64) {
    const int bx = blockIdx.x;
    const bool isK = (blockIdx.y != 0);

    if (bx >= 640) {                      // fused k_kn region: 128 blocks on y==1
        if (!isK) return;
        int wave = threadIdx.x >> 6, lane = threadIdx.x & 63;
        int kb = ((bx - 640) * 4 + wave) * 16;
        for (int r = 0; r < 16; ++r) {
            int k = kb + r;
            float s = 0.f;
            if (k < NK)
                for (int d = lane; d < DD; d += 64) {
                    float v = key[k * DD + d];
                    s += v * v;
                }
#pragma unroll
            for (int off = 32; off; off >>= 1) s += __shfl_down(s, off, 64);
            if (lane == 0) {
                kn[k] = (k < NK) ? s : 1e30f;
                fidx64[k] = 0xFFFFFFFFFFFFFFFFull;   // ws re-poisoned every launch
            }
        }
        return;
    }

    int t = bx * 256 + threadIdx.x;             // 0 .. 163839 (ARRN/8)
    int c = t >> 15;                            // chunk
    int rem = t & 32767;                        // g*64 + lane
    int col = ((rem >> 6) << 4) + (rem & 15);   // g*16 + l15
    int quad = (rem >> 4) & 3;
    int kbase = c * 32 + quad * 8;

    float v[8];
#pragma unroll
    for (int j = 0; j < 8; ++j) {
        int k = kbase + j;
        float x = 0.f;
        if (k < DD && col < NQ) {
            if (isK) {
                x = key[col * DD + k];
            } else {
                int c3 = k / 49, r2 = k - 49 * c3;
                int rr = r2 / 7, ss = r2 - 7 * rr;
                int y = col / HO, xx = col - HO * y;
                x = query[(c3 * IMG + y + rr) * IMG + xx + ss];
            }
        }
        v[j] = x;
    }
    half8 h8, l8;
#pragma unroll
    for (int j = 0; j < 8; ++j) {
        _Float16 h = (_Float16)v[j];
        h8[j] = h;
        l8[j] = (_Float16)(v[j] - (float)h);   // UNSCALED lo (merged-acc scheme)
    }
    if (isK) {
        *(half8*)(Kh + t * 8) = h8;
        *(half8*)(Kl + t * 8) = l8;
    } else {
        *(half8*)(Qh + t * 8) = h8;
        *(half8*)(Ql + t * 8) = l8;
    }
}

// ---------------- main: merged-acc split-f16 MFMA Q.K^T + fused argmin ----------------
// Barrier-free K-loop, single acc[4][4] (64 AGPR), 17.4KB epilogue LDS, 3 blocks/CU target.
__launch_bounds__(256, 3)
__global__ void k_nn(const _Float16* __restrict__ Qh, const _Float16* __restrict__ Ql,
                     const _Float16* __restrict__ Kh, const _Float16* __restrict__ Kl,
                     const float* __restrict__ kn, unsigned long long* __restrict__ out) {
    __shared__ __align__(16) char smem[17408];   // epilogue reduction: [128][17] u64

    const int tid = (int)threadIdx.x;
    const int wave = tid >> 6, lane = tid & 63;
    const int l15 = lane & 15, quad = lane >> 4;

    // XCD-aware swizzle: blockIdx%8 == XCD. Per XCD: 16qt x 32kt rectangle =>
    // Q 1.28 MB + K 2.56 MB = 3.84 MB <= 4 MiB L2.
    const int b = (int)blockIdx.x;
    const int xcd = b & 7;
    const int i = b >> 3;                         // 0..511 within XCD
    const int qt = (xcd >> 1) * 16 + (i & 15);
    const int kt = (xcd & 1) * 32 + (i >> 4);

    const int mbase = (wave >> 1) * 64;           // wave tile: 64x64 within 128x128
    const int nbase = (wave & 1) * 64;
    const int q0 = qt * 128, n0 = kt * 128;

    // frag-linear global bases (coalesced 16B/lane, L2-hot under the swizzle)
    const int agrp = (mbase >> 4);
    const int bgrp = (nbase >> 4);
    const _Float16* gQh = Qh + (qt * 8 + agrp) * 512 + lane * 8;
    const _Float16* gQl = Ql + (qt * 8 + agrp) * 512 + lane * 8;
    const _Float16* gKh = Kh + (kt * 8 + bgrp) * 512 + lane * 8;
    const _Float16* gKl = Kl + (kt * 8 + bgrp) * 512 + lane * 8;

    f32x4 acc[4][4];                              // single merged accumulator: 64 AGPR
#pragma unroll
    for (int ii = 0; ii < 4; ++ii)
#pragma unroll
        for (int j = 0; j < 4; ++j)
            acc[ii][j] = (f32x4)0.f;

#pragma unroll
    for (int c = 0; c < NCH; ++c) {
        // 16 independent coalesced loads; no barrier anywhere in the K-loop.
        half8 ah[4], al[4], bh[4], bl[4];
#pragma unroll
        for (int mt = 0; mt < 4; ++mt) {
            ah[mt] = *(const half8*)(gQh + c * CST + mt * 512);
            al[mt] = *(const half8*)(gQl + c * CST + mt * 512);
        }
#pragma unroll
        for (int nt = 0; nt < 4; ++nt) {
            bh[nt] = *(const half8*)(gKh + c * CST + nt * 512);
            bl[nt] = *(const half8*)(gKl + c * CST + nt * 512);
        }

        __builtin_amdgcn_s_setprio(1);
#pragma unroll
        for (int nt = 0; nt < 4; ++nt) {
#pragma unroll
            for (int mt = 0; mt < 4; ++mt) {
                acc[mt][nt] = __builtin_amdgcn_mfma_f32_16x16x32_f16(ah[mt], bh[nt], acc[mt][nt], 0, 0, 0);
                acc[mt][nt] = __builtin_amdgcn_mfma_f32_16x16x32_f16(ah[mt], bl[nt], acc[mt][nt], 0, 0, 0);
                acc[mt][nt] = __builtin_amdgcn_mfma_f32_16x16x32_f16(al[mt], bh[nt], acc[mt][nt], 0, 0, 0);
            }
        }
        __builtin_amdgcn_s_setprio(0);
    }

    // epilogue: dist = kn - 2*acc; packed order-preserving u64; shfl_xor(1) col-pair
    // pre-combine -> [128][17] u64 LDS (u64 lexicographic min == (value asc, idx asc)).
    float knv[4];
    int nglob[4];
#pragma unroll
    for (int nt = 0; nt < 4; ++nt) {
        nglob[nt] = n0 + nbase + nt * 16 + l15;
        knv[nt] = kn[nglob[nt]];
    }
    unsigned long long* redu = (unsigned long long*)smem;   // [128][17] u64
    const int cidx2 = (nbase >> 3) + (l15 >> 1);            // 0..15 after pair-combine

#pragma unroll
    for (int mt = 0; mt < 4; ++mt)
#pragma unroll
        for (int r = 0; r < 4; ++r) {
            float bv = 1e38f;
            int bn = 0x7fffffff;
#pragma unroll
            for (int nt = 0; nt < 4; ++nt) {   // ascending n within lane -> strict < ok
                float d = knv[nt] - 2.0f * acc[mt][nt][r];
                if (d < bv) { bv = d; bn = nglob[nt]; }
            }
            unsigned u = __float_as_uint(bv);
            u = (u & 0x80000000u) ? ~u : (u | 0x80000000u);   // order-preserving map
            unsigned long long pk = ((unsigned long long)u << 32) | (unsigned)bn;
            unsigned long long po = __shfl_xor(pk, 1, 64);    // partner col, same row
            pk = (po < pk) ? po : pk;
            if (!(lane & 1)) {
                int m = mbase + mt * 16 + quad * 4 + r;        // C row = quad*4 + reg
                redu[m * 17 + cidx2] = pk;
            }
        }
    __syncthreads();

    {   // 2 threads/row, 8 u64-min each, pair-combine via shfl
        int row = tid >> 1;
        int base = (tid & 1) * 8;
        unsigned long long best = 0xFFFFFFFFFFFFFFFFull;
        const unsigned long long* rp = redu + row * 17 + base;
#pragma unroll
        for (int t2 = 0; t2 < 8; ++t2) {
            unsigned long long v = rp[t2];
            best = (v < best) ? v : best;
        }
        unsigned long long other = __shfl_xor(best, 1, 64);
        best = (other < best) ? other : best;
        if (!(tid & 1)) atomicMin(&out[q0 + row], best);
    }
}

// ---------------- gather + fold (overlap-add mean) ----------------
// 8 lanes per output pixel: lane-slot s=0..6 handles patch-row i=s (7 j-loads, ILP 7),
// s=7 idle; shfl_down(width=8) tree reduces; s==0 divides by ANALYTIC count and stores.
// 864 blocks x 256 = 13.5 waves/CU.
__global__ void k_fold(const float* __restrict__ value,
                       const unsigned long long* __restrict__ fidx64,
                       float* __restrict__ out) {
    int t = blockIdx.x * 256 + threadIdx.x;   // 3*96*96*8 = 221184
    int pix = t >> 3, s = t & 7;
    if (pix >= 3 * IMG * IMG) return;
    int c = pix / (IMG * IMG);
    int rem = pix % (IMG * IMG);
    int Y = rem / IMG, X = rem % IMG;

    float partial = 0.f;
    int yy = Y - s;
    if (s < 7 && (unsigned)yy < (unsigned)HO) {
        const unsigned* fidx32 = (const unsigned*)fidx64;   // low word = row index
        const float* vbase = value + c * 49 + s * 7;
        int rows[7];
        bool oks[7];
#pragma unroll
        for (int j = 0; j < 7; ++j) {
            int xx = X - j;
            bool ok = (unsigned)xx < (unsigned)HO;
            int p = ok ? (yy * HO + xx) : 0;
            rows[j] = (int)fidx32[2 * p];
            oks[j] = ok;
        }
#pragma unroll
        for (int j = 0; j < 7; ++j) {
            float v = vbase[rows[j] * DD + j];   // always in-bounds (row 0 when masked)
            if (oks[j]) partial += v;
        }
    }
    partial += __shfl_down(partial, 4, 8);
    partial += __shfl_down(partial, 2, 8);
    partial += __shfl_down(partial, 1, 8);
    if (s == 0) {
        int i0 = max(0, Y - (HO - 1)), i1 = min(6, Y);
        int j0 = max(0, X - (HO - 1)), j1 = min(6, X);
        float cnt = (float)((i1 - i0 + 1) * (j1 - j0 + 1));
        out[pix] = partial / cnt;
    }
}

extern "C" void kernel_launch(void* const* d_in, const int* in_sizes, int n_in,
                              void* d_out, int out_size, void* d_ws, size_t ws_size,
                              hipStream_t stream) {
    const float* query = (const float*)d_in[0];
    const float* key   = (const float*)d_in[1];
    const float* value = (const float*)d_in[2];
    float* out = (float*)d_out;

    _Float16* Qh = (_Float16*)d_ws;           // ARRN f16 each
    _Float16* Ql = Qh + ARRN;
    _Float16* Kh = Ql + ARRN;
    _Float16* Kl = Kh + ARRN;
    float* kn = (float*)(Kl + ARRN);          // 8192 f32
    unsigned long long* fidx64 = (unsigned long long*)(kn + 8192);   // 8192 u64

    dim3 gp(768, 2);   // 640 split blocks + 128 fused-kn blocks (y==1)
    k_prep<<<gp, 256, 0, stream>>>(query, key, Qh, Ql, Kh, Kl, kn, fidx64);
    k_nn<<<4096, 256, 0, stream>>>(Qh, Ql, Kh, Kl, kn, fidx64);
    k_fold<<<864, 256, 0, stream>>>(value, fidx64, out);
}